// Round 2
// baseline (8328.157 us; speedup 1.0000x reference)
//
#include <hip/hip_runtime.h>

#define NN 200000
#define NE 400000
#define NFEAT 78
#define DIM 128
#define NLAYERS 5
#define NGRAPHS 8192
#define BN_EPS_C 1e-5f

// out[n][d] = maybe_relu(bias[d] + sum_k in[n][k]*W[k][d]); optional duplicate store to out2.
// Thread-per-node, 128 fp32 accumulators, wave-uniform weight loads.
template<int K>
__global__ __launch_bounds__(256) void dense_kernel(
    const float* __restrict__ in, const float* __restrict__ W,
    const float* __restrict__ bias, float* __restrict__ out,
    float* __restrict__ out2, int relu_out, int n_rows)
{
    int n = blockIdx.x * 256 + threadIdx.x;
    if (n >= n_rows) return;
    const float4* B4 = reinterpret_cast<const float4*>(bias);
    float4 acc[DIM / 4];
#pragma unroll
    for (int j = 0; j < DIM / 4; ++j) acc[j] = B4[j];
    const float* __restrict__ row = in + (size_t)n * K;
    const float4* __restrict__ W4 = reinterpret_cast<const float4*>(W);
    for (int k = 0; k < K; ++k) {
        float xk = row[k];
#pragma unroll
        for (int j = 0; j < DIM / 4; ++j) {
            float4 w = W4[k * (DIM / 4) + j];
            acc[j].x = fmaf(xk, w.x, acc[j].x);
            acc[j].y = fmaf(xk, w.y, acc[j].y);
            acc[j].z = fmaf(xk, w.z, acc[j].z);
            acc[j].w = fmaf(xk, w.w, acc[j].w);
        }
    }
    if (relu_out) {
#pragma unroll
        for (int j = 0; j < DIM / 4; ++j) {
            acc[j].x = fmaxf(acc[j].x, 0.f);
            acc[j].y = fmaxf(acc[j].y, 0.f);
            acc[j].z = fmaxf(acc[j].z, 0.f);
            acc[j].w = fmaxf(acc[j].w, 0.f);
        }
    }
    float4* o = reinterpret_cast<float4*>(out + (size_t)n * DIM);
#pragma unroll
    for (int j = 0; j < DIM / 4; ++j) o[j] = acc[j];
    if (out2) {
        float4* o2 = reinterpret_cast<float4*>(out2 + (size_t)n * DIM);
#pragma unroll
        for (int j = 0; j < DIM / 4; ++j) o2[j] = acc[j];
    }
}

// agg[dst] += h[src] for each edge; agg pre-seeded with h (self term).
// One thread per (edge, 4-feature chunk): 32 threads per edge, coalesced float4 gather.
__global__ __launch_bounds__(256) void scatter_kernel(
    const float* __restrict__ h, const int* __restrict__ ei,
    float* __restrict__ agg)
{
    long long idx = (long long)blockIdx.x * 256 + threadIdx.x;
    if (idx >= (long long)NE * 32) return;
    int e = (int)(idx >> 5);
    int j = (int)(idx & 31);
    int s = ei[e];
    int d = ei[NE + e];
    float4 v = *reinterpret_cast<const float4*>(h + (size_t)s * DIM + j * 4);
    float* a = agg + (size_t)d * DIM + j * 4;
    atomicAdd(a + 0, v.x);
    atomicAdd(a + 1, v.y);
    atomicAdd(a + 2, v.z);
    atomicAdd(a + 3, v.w);
}

// Per-feature column sums and sumsq over all nodes -> stats[0:128]=sum, stats[128:256]=sumsq
__global__ __launch_bounds__(256) void stats_kernel(
    const float* __restrict__ z, float* __restrict__ stats)
{
    int d = threadIdx.x & (DIM - 1);
    int r = threadIdx.x >> 7;            // 0..1
    int stride = gridDim.x * 2;
    float s = 0.f, sq = 0.f;
    for (int n = blockIdx.x * 2 + r; n < NN; n += stride) {
        float v = z[(size_t)n * DIM + d];
        s += v;
        sq += v * v;
    }
    atomicAdd(&stats[d], s);
    atomicAdd(&stats[DIM + d], sq);
}

// affine[d] = gamma*rsqrt(var+eps); affine[128+d] = beta - mean*affine[d]
__global__ void finalize_kernel(
    const float* __restrict__ stats, const float* __restrict__ gamma,
    const float* __restrict__ beta, float* __restrict__ affine)
{
    int d = threadIdx.x;
    float mean = stats[d] * (1.0f / NN);
    float var = stats[DIM + d] * (1.0f / NN) - mean * mean;
    float a = gamma[d] * rsqrtf(var + BN_EPS_C);
    affine[d] = a;
    affine[DIM + d] = beta[d] - mean * a;
}

// h = a*z + c (z == agg, in place read-then-write per thread);
// also duplicate h into agg (seed for next layer's scatter) unless last layer.
__global__ __launch_bounds__(256) void bn_apply_kernel(
    const float* __restrict__ z, const float* __restrict__ affine,
    float* __restrict__ h, float* __restrict__ agg, int last)
{
    long long idx = (long long)blockIdx.x * 256 + threadIdx.x;
    if (idx >= (long long)NN * (DIM / 4)) return;
    int j = (int)(idx & (DIM / 4 - 1));
    float4 z4 = reinterpret_cast<const float4*>(z)[idx];
    float4 a4 = reinterpret_cast<const float4*>(affine)[j];
    float4 c4 = reinterpret_cast<const float4*>(affine + DIM)[j];
    float4 h4;
    h4.x = fmaf(a4.x, z4.x, c4.x);
    h4.y = fmaf(a4.y, z4.y, c4.y);
    h4.z = fmaf(a4.z, z4.z, c4.z);
    h4.w = fmaf(a4.w, z4.w, c4.w);
    reinterpret_cast<float4*>(h)[idx] = h4;
    if (!last) reinterpret_cast<float4*>(agg)[idx] = h4;
}

// Sorted-segment pooling with layer weight:
// out[g][d] += sum over contiguous nodes of (w*h[n][d] + (add_lcb ? lcb : 0))
#define POOL_NPB 256
__global__ __launch_bounds__(128) void pool_kernel(
    const float* __restrict__ h, const int* __restrict__ batch,
    const float* __restrict__ lcw, int l, const float* __restrict__ lcb_p,
    int add_lcb, float* __restrict__ out)
{
    int d = threadIdx.x;
    int n0 = blockIdx.x * POOL_NPB;
    int nend = n0 + POOL_NPB;
    if (nend > NN) nend = NN;
    float w = lcw[l];
    float lcb = add_lcb ? *lcb_p : 0.f;
    float acc = 0.f;
    int cur = -1;
    for (int n = n0; n < nend; ++n) {
        int g = batch[n];
        if (g != cur) {
            if (cur >= 0) atomicAdd(&out[(size_t)cur * DIM + d], acc);
            cur = g;
            acc = 0.f;
        }
        acc = fmaf(w, h[(size_t)n * DIM + d], acc) + lcb;
    }
    if (cur >= 0) atomicAdd(&out[(size_t)cur * DIM + d], acc);
}

extern "C" void kernel_launch(void* const* d_in, const int* in_sizes, int n_in,
                              void* d_out, int out_size, void* d_ws, size_t ws_size,
                              hipStream_t stream)
{
    const float* x      = (const float*)d_in[0];
    const int*   ei     = (const int*)d_in[1];
    const int*   batch  = (const int*)d_in[2];
    const float* ini_w1 = (const float*)d_in[4];
    const float* ini_b1 = (const float*)d_in[5];
    const float* ini_w2 = (const float*)d_in[6];
    const float* ini_b2 = (const float*)d_in[7];
    const float* gw1    = (const float*)d_in[8];
    const float* gb1    = (const float*)d_in[9];
    const float* gw2    = (const float*)d_in[10];
    const float* gb2    = (const float*)d_in[11];
    const float* gamma  = (const float*)d_in[12];
    const float* beta   = (const float*)d_in[13];
    const float* lcw    = (const float*)d_in[14];
    const float* lcb    = (const float*)d_in[15];
    float* out = (float*)d_out;

    size_t NH = (size_t)NN * DIM;
    size_t need = (2 * NH + 2 * NLAYERS * 256) * sizeof(float);

    hipMemsetAsync(out, 0, (size_t)NGRAPHS * DIM * sizeof(float), stream);
    if (ws_size < need) return;   // diagnostic: zero output => absmax ~= 488 signals ws shortfall

    float* h      = (float*)d_ws;
    float* agg    = h + NH;
    float* stats  = agg + NH;            // NLAYERS*256 floats
    float* affine = stats + NLAYERS * 256;

    hipMemsetAsync(stats, 0, NLAYERS * 256 * sizeof(float), stream);

    int dense_blocks = (NN + 255) / 256;

    // ini_embed: agg = relu(x@w1+b1) ; h = agg@w2+b2 ; agg = h (dup store)
    dense_kernel<NFEAT><<<dense_blocks, 256, 0, stream>>>(x, ini_w1, ini_b1, agg, nullptr, 1, NN);
    dense_kernel<DIM><<<dense_blocks, 256, 0, stream>>>(agg, ini_w2, ini_b2, h, agg, 0, NN);

    long long sc_threads = (long long)NE * 32;
    int sc_blocks = (int)((sc_threads + 255) / 256);
    long long bn_threads = (long long)NN * (DIM / 4);
    int bn_blocks = (int)((bn_threads + 255) / 256);
    int pool_blocks = (NN + POOL_NPB - 1) / POOL_NPB;

    for (int l = 0; l < NLAYERS; ++l) {
        // agg currently = h; add neighbor contributions
        scatter_kernel<<<sc_blocks, 256, 0, stream>>>(h, ei, agg);
        // h <- relu(agg @ w1 + b1)
        dense_kernel<DIM><<<dense_blocks, 256, 0, stream>>>(
            agg, gw1 + (size_t)l * DIM * DIM, gb1 + l * DIM, h, nullptr, 1, NN);
        // agg <- relu(h @ w2 + b2)   (z2, post-relu pre-BN)
        dense_kernel<DIM><<<dense_blocks, 256, 0, stream>>>(
            h, gw2 + (size_t)l * DIM * DIM, gb2 + l * DIM, agg, nullptr, 1, NN);
        // batch stats over agg
        stats_kernel<<<1024, 256, 0, stream>>>(agg, stats + l * 256);
        finalize_kernel<<<1, 128, 0, stream>>>(
            stats + l * 256, gamma + l * DIM, beta + l * DIM, affine + l * 256);
        // h = BN(agg); agg = h (seed next layer) unless last
        bn_apply_kernel<<<bn_blocks, 256, 0, stream>>>(
            agg, affine + l * 256, h, agg, (l == NLAYERS - 1) ? 1 : 0);
        // out += lcw[l] * segsum(h)  (+ lcb per node on layer 0)
        pool_kernel<<<pool_blocks, 128, 0, stream>>>(
            h, batch, lcw, l, lcb, (l == 0) ? 1 : 0, out);
    }
}

// Round 3
// 5358.822 us; speedup vs baseline: 1.5541x; 1.5541x over previous
//
#include <hip/hip_runtime.h>

#define NN 200000
#define NE 400000
#define NFEAT 78
#define DIM 128
#define NLAYERS 5
#define NGRAPHS 8192
#define BN_EPS_C 1e-5f

// out[n][d] = maybe_relu(bias[d] + sum_k in[n][k]*W[k][d])
template<int K>
__global__ __launch_bounds__(256) void dense_kernel(
    const float* __restrict__ in, const float* __restrict__ W,
    const float* __restrict__ bias, float* __restrict__ out,
    int relu_out, int n_rows)
{
    int n = blockIdx.x * 256 + threadIdx.x;
    if (n >= n_rows) return;
    const float4* B4 = reinterpret_cast<const float4*>(bias);
    float4 acc[DIM / 4];
#pragma unroll
    for (int j = 0; j < DIM / 4; ++j) acc[j] = B4[j];
    const float* __restrict__ row = in + (size_t)n * K;
    const float4* __restrict__ W4 = reinterpret_cast<const float4*>(W);
    for (int k = 0; k < K; ++k) {
        float xk = row[k];
#pragma unroll
        for (int j = 0; j < DIM / 4; ++j) {
            float4 w = W4[k * (DIM / 4) + j];
            acc[j].x = fmaf(xk, w.x, acc[j].x);
            acc[j].y = fmaf(xk, w.y, acc[j].y);
            acc[j].z = fmaf(xk, w.z, acc[j].z);
            acc[j].w = fmaf(xk, w.w, acc[j].w);
        }
    }
    if (relu_out) {
#pragma unroll
        for (int j = 0; j < DIM / 4; ++j) {
            acc[j].x = fmaxf(acc[j].x, 0.f);
            acc[j].y = fmaxf(acc[j].y, 0.f);
            acc[j].z = fmaxf(acc[j].z, 0.f);
            acc[j].w = fmaxf(acc[j].w, 0.f);
        }
    }
    float4* o = reinterpret_cast<float4*>(out + (size_t)n * DIM);
#pragma unroll
    for (int j = 0; j < DIM / 4; ++j) o[j] = acc[j];
}

// ---------- CSR build (once per launch) ----------
__global__ __launch_bounds__(256) void deg_kernel(
    const int* __restrict__ ei, int* __restrict__ deg)
{
    int e = blockIdx.x * 256 + threadIdx.x;
    if (e >= NE) return;
    atomicAdd(&deg[ei[NE + e]], 1);
}

// Per-block exclusive scan of deg -> cursor; block totals -> partials
__global__ __launch_bounds__(256) void scanA_kernel(
    const int* __restrict__ deg, int* __restrict__ cursor,
    int* __restrict__ partials)
{
    __shared__ int sh[256];
    int i = blockIdx.x * 256 + threadIdx.x;
    int v = (i < NN) ? deg[i] : 0;
    sh[threadIdx.x] = v;
    __syncthreads();
    for (int off = 1; off < 256; off <<= 1) {
        int t = (threadIdx.x >= off) ? sh[threadIdx.x - off] : 0;
        __syncthreads();
        sh[threadIdx.x] += t;
        __syncthreads();
    }
    int incl = sh[threadIdx.x];
    if (i < NN) cursor[i] = incl - v;           // exclusive
    if (threadIdx.x == 255) partials[blockIdx.x] = incl;
}

// Exclusive scan of partials (nb <= 1024) in one block
__global__ __launch_bounds__(1024) void scanB_kernel(int* __restrict__ partials, int nb)
{
    __shared__ int sh[1024];
    int i = threadIdx.x;
    int v = (i < nb) ? partials[i] : 0;
    sh[i] = v;
    __syncthreads();
    for (int off = 1; off < 1024; off <<= 1) {
        int t = (i >= off) ? sh[i - off] : 0;
        __syncthreads();
        sh[i] += t;
        __syncthreads();
    }
    if (i < nb) partials[i] = sh[i] - v;        // exclusive
}

__global__ __launch_bounds__(256) void scanC_kernel(
    int* __restrict__ cursor, const int* __restrict__ partials)
{
    int i = blockIdx.x * 256 + threadIdx.x;
    if (i < NN) cursor[i] += partials[blockIdx.x];
}

// fill: slot = cursor[dst]++; csr_src[slot] = src. After this, cursor[n] = end-offset of node n.
__global__ __launch_bounds__(256) void fill_kernel(
    const int* __restrict__ ei, int* __restrict__ cursor,
    int* __restrict__ csr_src)
{
    int e = blockIdx.x * 256 + threadIdx.x;
    if (e >= NE) return;
    int slot = atomicAdd(&cursor[ei[NE + e]], 1);
    csr_src[slot] = ei[e];
}

// agg[n] = h[n] + sum_{i in [beg,end)} h[csr_src[i]] ; 32 lanes per node (float4 j=lane)
__global__ __launch_bounds__(256) void gather_kernel(
    const float* __restrict__ h, const int* __restrict__ cursor,
    const int* __restrict__ csr_src, float* __restrict__ agg)
{
    long long t = (long long)blockIdx.x * 256 + threadIdx.x;
    int n = (int)(t >> 5);
    int j = (int)(t & 31);
    if (n >= NN) return;
    int end = cursor[n];
    int beg = (n == 0) ? 0 : cursor[n - 1];
    float4 acc = *reinterpret_cast<const float4*>(h + (size_t)n * DIM + j * 4);
    for (int i = beg; i < end; ++i) {
        int s = csr_src[i];
        float4 v = *reinterpret_cast<const float4*>(h + (size_t)s * DIM + j * 4);
        acc.x += v.x; acc.y += v.y; acc.z += v.z; acc.w += v.w;
    }
    *reinterpret_cast<float4*>(agg + (size_t)n * DIM + j * 4) = acc;
}

// Per-feature column sums and sumsq -> stats[0:128]=sum, stats[128:256]=sumsq
__global__ __launch_bounds__(256) void stats_kernel(
    const float* __restrict__ z, float* __restrict__ stats)
{
    int d = threadIdx.x & (DIM - 1);
    int r = threadIdx.x >> 7;
    int stride = gridDim.x * 2;
    float s = 0.f, sq = 0.f;
    for (int n = blockIdx.x * 2 + r; n < NN; n += stride) {
        float v = z[(size_t)n * DIM + d];
        s += v;
        sq += v * v;
    }
    atomicAdd(&stats[d], s);
    atomicAdd(&stats[DIM + d], sq);
}

__global__ void finalize_kernel(
    const float* __restrict__ stats, const float* __restrict__ gamma,
    const float* __restrict__ beta, float* __restrict__ affine)
{
    int d = threadIdx.x;
    float mean = stats[d] * (1.0f / NN);
    float var = stats[DIM + d] * (1.0f / NN) - mean * mean;
    float a = gamma[d] * rsqrtf(var + BN_EPS_C);
    affine[d] = a;
    affine[DIM + d] = beta[d] - mean * a;
}

// h = a*z + c
__global__ __launch_bounds__(256) void bn_apply_kernel(
    const float* __restrict__ z, const float* __restrict__ affine,
    float* __restrict__ h)
{
    long long idx = (long long)blockIdx.x * 256 + threadIdx.x;
    if (idx >= (long long)NN * (DIM / 4)) return;
    int j = (int)(idx & (DIM / 4 - 1));
    float4 z4 = reinterpret_cast<const float4*>(z)[idx];
    float4 a4 = reinterpret_cast<const float4*>(affine)[j];
    float4 c4 = reinterpret_cast<const float4*>(affine + DIM)[j];
    float4 h4;
    h4.x = fmaf(a4.x, z4.x, c4.x);
    h4.y = fmaf(a4.y, z4.y, c4.y);
    h4.z = fmaf(a4.z, z4.z, c4.z);
    h4.w = fmaf(a4.w, z4.w, c4.w);
    reinterpret_cast<float4*>(h)[idx] = h4;
}

// out[g][d] += sum over contiguous nodes of (w*h[n][d] + (add_lcb ? lcb : 0))
#define POOL_NPB 256
__global__ __launch_bounds__(128) void pool_kernel(
    const float* __restrict__ h, const int* __restrict__ batch,
    const float* __restrict__ lcw, int l, const float* __restrict__ lcb_p,
    int add_lcb, float* __restrict__ out)
{
    int d = threadIdx.x;
    int n0 = blockIdx.x * POOL_NPB;
    int nend = n0 + POOL_NPB;
    if (nend > NN) nend = NN;
    float w = lcw[l];
    float lcb = add_lcb ? *lcb_p : 0.f;
    float acc = 0.f;
    int cur = -1;
    for (int n = n0; n < nend; ++n) {
        int g = batch[n];
        if (g != cur) {
            if (cur >= 0) atomicAdd(&out[(size_t)cur * DIM + d], acc);
            cur = g;
            acc = 0.f;
        }
        acc = fmaf(w, h[(size_t)n * DIM + d], acc) + lcb;
    }
    if (cur >= 0) atomicAdd(&out[(size_t)cur * DIM + d], acc);
}

extern "C" void kernel_launch(void* const* d_in, const int* in_sizes, int n_in,
                              void* d_out, int out_size, void* d_ws, size_t ws_size,
                              hipStream_t stream)
{
    const float* x      = (const float*)d_in[0];
    const int*   ei     = (const int*)d_in[1];
    const int*   batch  = (const int*)d_in[2];
    const float* ini_w1 = (const float*)d_in[4];
    const float* ini_b1 = (const float*)d_in[5];
    const float* ini_w2 = (const float*)d_in[6];
    const float* ini_b2 = (const float*)d_in[7];
    const float* gw1    = (const float*)d_in[8];
    const float* gb1    = (const float*)d_in[9];
    const float* gw2    = (const float*)d_in[10];
    const float* gb2    = (const float*)d_in[11];
    const float* gamma  = (const float*)d_in[12];
    const float* beta   = (const float*)d_in[13];
    const float* lcw    = (const float*)d_in[14];
    const float* lcb    = (const float*)d_in[15];
    float* out = (float*)d_out;

    size_t NH = (size_t)NN * DIM;
    size_t need = (2 * NH + 2 * NLAYERS * 256) * sizeof(float)
                + (size_t)(2 * NN + NE + 1024) * sizeof(int);

    hipMemsetAsync(out, 0, (size_t)NGRAPHS * DIM * sizeof(float), stream);
    if (ws_size < need) return;   // diagnostic: zero output signals ws shortfall

    float* h      = (float*)d_ws;
    float* agg    = h + NH;
    float* stats  = agg + NH;
    float* affine = stats + NLAYERS * 256;
    int* deg      = (int*)(affine + NLAYERS * 256);
    int* cursor   = deg + NN;
    int* csr_src  = cursor + NN;
    int* partials = csr_src + NE;

    hipMemsetAsync(stats, 0, NLAYERS * 256 * sizeof(float), stream);
    hipMemsetAsync(deg, 0, NN * sizeof(int), stream);

    int nb = (NN + 255) / 256;            // 782 scan blocks (fits scanB's 1024)
    int eb = (NE + 255) / 256;

    // ---- CSR build (once) ----
    deg_kernel<<<eb, 256, 0, stream>>>(ei, deg);
    scanA_kernel<<<nb, 256, 0, stream>>>(deg, cursor, partials);
    scanB_kernel<<<1, 1024, 0, stream>>>(partials, nb);
    scanC_kernel<<<nb, 256, 0, stream>>>(cursor, partials);
    fill_kernel<<<eb, 256, 0, stream>>>(ei, cursor, csr_src);

    int dense_blocks = (NN + 255) / 256;

    // ini_embed: agg = relu(x@w1+b1) ; h = agg@w2+b2
    dense_kernel<NFEAT><<<dense_blocks, 256, 0, stream>>>(x, ini_w1, ini_b1, agg, 1, NN);
    dense_kernel<DIM><<<dense_blocks, 256, 0, stream>>>(agg, ini_w2, ini_b2, h, 0, NN);

    long long g_threads = (long long)NN * 32;
    int g_blocks = (int)((g_threads + 255) / 256);
    long long bn_threads = (long long)NN * (DIM / 4);
    int bn_blocks = (int)((bn_threads + 255) / 256);
    int pool_blocks = (NN + POOL_NPB - 1) / POOL_NPB;

    for (int l = 0; l < NLAYERS; ++l) {
        // agg = h + neighbor sum
        gather_kernel<<<g_blocks, 256, 0, stream>>>(h, cursor, csr_src, agg);
        // h <- relu(agg @ w1 + b1)
        dense_kernel<DIM><<<dense_blocks, 256, 0, stream>>>(
            agg, gw1 + (size_t)l * DIM * DIM, gb1 + l * DIM, h, 1, NN);
        // agg <- relu(h @ w2 + b2)
        dense_kernel<DIM><<<dense_blocks, 256, 0, stream>>>(
            h, gw2 + (size_t)l * DIM * DIM, gb2 + l * DIM, agg, 1, NN);
        // batch stats + affine
        stats_kernel<<<1024, 256, 0, stream>>>(agg, stats + l * 256);
        finalize_kernel<<<1, 128, 0, stream>>>(
            stats + l * 256, gamma + l * DIM, beta + l * DIM, affine + l * 256);
        // h = BN(agg)
        bn_apply_kernel<<<bn_blocks, 256, 0, stream>>>(agg, affine + l * 256, h);
        // out += lcw[l] * segsum(h)  (+ lcb per node on layer 0)
        pool_kernel<<<pool_blocks, 128, 0, stream>>>(
            h, batch, lcw, l, lcb, (l == 0) ? 1 : 0, out);
    }
}

// Round 4
// 3257.235 us; speedup vs baseline: 2.5568x; 1.6452x over previous
//
#include <hip/hip_runtime.h>

#define NN 200000
#define NE 400000
#define NFEAT 78
#define DIM 128
#define NLAYERS 5
#define NGRAPHS 8192
#define BN_EPS_C 1e-5f

// Each block: 256 threads (thread-per-node), 64 output cols selected by blockIdx.y.
// A-row loads vectorized by CHUNK (float4 for K%4==0, float2 for K%2==0).
// W address is wave-uniform -> scalarized to s_load broadcasts.
template<int K, int CHUNK, int RELU>
__global__ __launch_bounds__(256, 5) void dense64_kernel(
    const float* __restrict__ in, const float* __restrict__ W,
    const float* __restrict__ bias, float* __restrict__ out)
{
    int n = blockIdx.x * 256 + threadIdx.x;
    if (n >= NN) return;
    int c0 = blockIdx.y * 64;
    float4 acc[16];
    const float4* B4 = reinterpret_cast<const float4*>(bias + c0);
#pragma unroll
    for (int j = 0; j < 16; ++j) acc[j] = B4[j];
    const float* __restrict__ row = in + (size_t)n * K;
    const float* __restrict__ Wp = W + c0;
#pragma unroll 2
    for (int k = 0; k < K; k += CHUNK) {
        float a[CHUNK];
        if (CHUNK == 4) {
            float4 v = *reinterpret_cast<const float4*>(row + k);
            a[0] = v.x; a[1] = v.y; a[2] = v.z; a[3 % CHUNK] = v.w;
        } else {
            float2 v = *reinterpret_cast<const float2*>(row + k);
            a[0] = v.x; a[1] = v.y;
        }
#pragma unroll
        for (int kk = 0; kk < CHUNK; ++kk) {
            const float4* W4 = reinterpret_cast<const float4*>(Wp + (size_t)(k + kk) * DIM);
            float xk = a[kk];
#pragma unroll
            for (int j = 0; j < 16; ++j) {
                float4 w = W4[j];
                acc[j].x = fmaf(xk, w.x, acc[j].x);
                acc[j].y = fmaf(xk, w.y, acc[j].y);
                acc[j].z = fmaf(xk, w.z, acc[j].z);
                acc[j].w = fmaf(xk, w.w, acc[j].w);
            }
        }
    }
    if (RELU) {
#pragma unroll
        for (int j = 0; j < 16; ++j) {
            acc[j].x = fmaxf(acc[j].x, 0.f);
            acc[j].y = fmaxf(acc[j].y, 0.f);
            acc[j].z = fmaxf(acc[j].z, 0.f);
            acc[j].w = fmaxf(acc[j].w, 0.f);
        }
    }
    float4* o = reinterpret_cast<float4*>(out + (size_t)n * DIM + c0);
#pragma unroll
    for (int j = 0; j < 16; ++j) o[j] = acc[j];
}

// ---------- CSR build (once per launch) ----------
__global__ __launch_bounds__(256) void deg_kernel(
    const int* __restrict__ ei, int* __restrict__ deg)
{
    int e = blockIdx.x * 256 + threadIdx.x;
    if (e >= NE) return;
    atomicAdd(&deg[ei[NE + e]], 1);
}

__global__ __launch_bounds__(256) void scanA_kernel(
    const int* __restrict__ deg, int* __restrict__ cursor,
    int* __restrict__ partials)
{
    __shared__ int sh[256];
    int i = blockIdx.x * 256 + threadIdx.x;
    int v = (i < NN) ? deg[i] : 0;
    sh[threadIdx.x] = v;
    __syncthreads();
    for (int off = 1; off < 256; off <<= 1) {
        int t = (threadIdx.x >= off) ? sh[threadIdx.x - off] : 0;
        __syncthreads();
        sh[threadIdx.x] += t;
        __syncthreads();
    }
    int incl = sh[threadIdx.x];
    if (i < NN) cursor[i] = incl - v;
    if (threadIdx.x == 255) partials[blockIdx.x] = incl;
}

__global__ __launch_bounds__(1024) void scanB_kernel(int* __restrict__ partials, int nb)
{
    __shared__ int sh[1024];
    int i = threadIdx.x;
    int v = (i < nb) ? partials[i] : 0;
    sh[i] = v;
    __syncthreads();
    for (int off = 1; off < 1024; off <<= 1) {
        int t = (i >= off) ? sh[i - off] : 0;
        __syncthreads();
        sh[i] += t;
        __syncthreads();
    }
    if (i < nb) partials[i] = sh[i] - v;
}

__global__ __launch_bounds__(256) void scanC_kernel(
    int* __restrict__ cursor, const int* __restrict__ partials)
{
    int i = blockIdx.x * 256 + threadIdx.x;
    if (i < NN) cursor[i] += partials[blockIdx.x];
}

__global__ __launch_bounds__(256) void fill_kernel(
    const int* __restrict__ ei, int* __restrict__ cursor,
    int* __restrict__ csr_src)
{
    int e = blockIdx.x * 256 + threadIdx.x;
    if (e >= NE) return;
    int slot = atomicAdd(&cursor[ei[NE + e]], 1);
    csr_src[slot] = ei[e];
}

// agg[n] = h[n] + sum_{i in [beg,end)} h[csr_src[i]] ; 32 lanes per node (float4 j=lane)
__global__ __launch_bounds__(256) void gather_kernel(
    const float* __restrict__ h, const int* __restrict__ cursor,
    const int* __restrict__ csr_src, float* __restrict__ agg)
{
    long long t = (long long)blockIdx.x * 256 + threadIdx.x;
    int n = (int)(t >> 5);
    int j = (int)(t & 31);
    if (n >= NN) return;
    int end = cursor[n];
    int beg = (n == 0) ? 0 : cursor[n - 1];
    float4 acc = *reinterpret_cast<const float4*>(h + (size_t)n * DIM + j * 4);
    for (int i = beg; i < end; ++i) {
        int s = csr_src[i];
        float4 v = *reinterpret_cast<const float4*>(h + (size_t)s * DIM + j * 4);
        acc.x += v.x; acc.y += v.y; acc.z += v.z; acc.w += v.w;
    }
    *reinterpret_cast<float4*>(agg + (size_t)n * DIM + j * 4) = acc;
}

// Per-feature column sums and sumsq -> stats[0:128]=sum, stats[128:256]=sumsq
__global__ __launch_bounds__(256) void stats_kernel(
    const float* __restrict__ z, float* __restrict__ stats)
{
    int d = threadIdx.x & (DIM - 1);
    int r = threadIdx.x >> 7;
    int stride = gridDim.x * 2;
    float s = 0.f, sq = 0.f;
    for (int n = blockIdx.x * 2 + r; n < NN; n += stride) {
        float v = z[(size_t)n * DIM + d];
        s += v;
        sq += v * v;
    }
    atomicAdd(&stats[d], s);
    atomicAdd(&stats[DIM + d], sq);
}

__global__ void finalize_kernel(
    const float* __restrict__ stats, const float* __restrict__ gamma,
    const float* __restrict__ beta, float* __restrict__ affine)
{
    int d = threadIdx.x;
    float mean = stats[d] * (1.0f / NN);
    float var = stats[DIM + d] * (1.0f / NN) - mean * mean;
    float a = gamma[d] * rsqrtf(var + BN_EPS_C);
    affine[d] = a;
    affine[DIM + d] = beta[d] - mean * a;
}

// Fused BN-apply + pool: h = a*z + c ; out[g][d] += w*h + lcb (sorted-run atomics).
// write_h=0 on the last layer (h not needed afterwards).
#define BP_NPB 256
__global__ __launch_bounds__(128) void bnpool_kernel(
    const float* __restrict__ z, const float* __restrict__ affine,
    const int* __restrict__ batch, const float* __restrict__ lcw, int l,
    const float* __restrict__ lcb_p, int add_lcb, int write_h,
    float* __restrict__ h, float* __restrict__ out)
{
    int d = threadIdx.x;
    int n0 = blockIdx.x * BP_NPB;
    int nend = n0 + BP_NPB;
    if (nend > NN) nend = NN;
    float a = affine[d];
    float c = affine[DIM + d];
    float w = lcw[l];
    float lcb = add_lcb ? *lcb_p : 0.f;
    float acc = 0.f;
    int cur = -1;
    for (int n = n0; n < nend; ++n) {
        float zv = z[(size_t)n * DIM + d];
        float hv = fmaf(a, zv, c);
        if (write_h) h[(size_t)n * DIM + d] = hv;
        int g = batch[n];
        if (g != cur) {
            if (cur >= 0) atomicAdd(&out[(size_t)cur * DIM + d], acc);
            cur = g;
            acc = 0.f;
        }
        acc = fmaf(w, hv, acc) + lcb;
    }
    if (cur >= 0) atomicAdd(&out[(size_t)cur * DIM + d], acc);
}

extern "C" void kernel_launch(void* const* d_in, const int* in_sizes, int n_in,
                              void* d_out, int out_size, void* d_ws, size_t ws_size,
                              hipStream_t stream)
{
    const float* x      = (const float*)d_in[0];
    const int*   ei     = (const int*)d_in[1];
    const int*   batch  = (const int*)d_in[2];
    const float* ini_w1 = (const float*)d_in[4];
    const float* ini_b1 = (const float*)d_in[5];
    const float* ini_w2 = (const float*)d_in[6];
    const float* ini_b2 = (const float*)d_in[7];
    const float* gw1    = (const float*)d_in[8];
    const float* gb1    = (const float*)d_in[9];
    const float* gw2    = (const float*)d_in[10];
    const float* gb2    = (const float*)d_in[11];
    const float* gamma  = (const float*)d_in[12];
    const float* beta   = (const float*)d_in[13];
    const float* lcw    = (const float*)d_in[14];
    const float* lcb    = (const float*)d_in[15];
    float* out = (float*)d_out;

    size_t NH = (size_t)NN * DIM;
    size_t need = (2 * NH + 2 * NLAYERS * 256) * sizeof(float)
                + (size_t)(2 * NN + NE + 1024) * sizeof(int);

    hipMemsetAsync(out, 0, (size_t)NGRAPHS * DIM * sizeof(float), stream);
    if (ws_size < need) return;   // diagnostic: zero output signals ws shortfall

    float* h      = (float*)d_ws;
    float* agg    = h + NH;
    float* stats  = agg + NH;
    float* affine = stats + NLAYERS * 256;
    int* deg      = (int*)(affine + NLAYERS * 256);
    int* cursor   = deg + NN;
    int* csr_src  = cursor + NN;
    int* partials = csr_src + NE;

    hipMemsetAsync(stats, 0, NLAYERS * 256 * sizeof(float), stream);
    hipMemsetAsync(deg, 0, NN * sizeof(int), stream);

    int nb = (NN + 255) / 256;
    int eb = (NE + 255) / 256;

    deg_kernel<<<eb, 256, 0, stream>>>(ei, deg);
    scanA_kernel<<<nb, 256, 0, stream>>>(deg, cursor, partials);
    scanB_kernel<<<1, 1024, 0, stream>>>(partials, nb);
    scanC_kernel<<<nb, 256, 0, stream>>>(cursor, partials);
    fill_kernel<<<eb, 256, 0, stream>>>(ei, cursor, csr_src);

    dim3 dgrid(nb, 2);

    // ini_embed: agg = relu(x@w1+b1) ; h = agg@w2+b2
    dense64_kernel<NFEAT, 2, 1><<<dgrid, 256, 0, stream>>>(x, ini_w1, ini_b1, agg);
    dense64_kernel<DIM, 4, 0><<<dgrid, 256, 0, stream>>>(agg, ini_w2, ini_b2, h);

    long long g_threads = (long long)NN * 32;
    int g_blocks = (int)((g_threads + 255) / 256);
    int bp_blocks = (NN + BP_NPB - 1) / BP_NPB;

    for (int l = 0; l < NLAYERS; ++l) {
        // agg = h + neighbor sum
        gather_kernel<<<g_blocks, 256, 0, stream>>>(h, cursor, csr_src, agg);
        // h <- relu(agg @ w1 + b1)
        dense64_kernel<DIM, 4, 1><<<dgrid, 256, 0, stream>>>(
            agg, gw1 + (size_t)l * DIM * DIM, gb1 + l * DIM, h);
        // agg <- relu(h @ w2 + b2)
        dense64_kernel<DIM, 4, 1><<<dgrid, 256, 0, stream>>>(
            h, gw2 + (size_t)l * DIM * DIM, gb2 + l * DIM, agg);
        // batch stats + affine
        stats_kernel<<<1024, 256, 0, stream>>>(agg, stats + l * 256);
        finalize_kernel<<<1, 128, 0, stream>>>(
            stats + l * 256, gamma + l * DIM, beta + l * DIM, affine + l * 256);
        // h = BN(agg); fused pool into out
        bnpool_kernel<<<bp_blocks, 128, 0, stream>>>(
            agg, affine + l * 256, batch, lcw, l, lcb,
            (l == 0) ? 1 : 0, (l == NLAYERS - 1) ? 0 : 1, h, out);
    }
}

// Round 5
// 1281.812 us; speedup vs baseline: 6.4972x; 2.5411x over previous
//
#include <hip/hip_runtime.h>

#define NN 200000
#define NE 400000
#define NFEAT 78
#define DIM 128
#define NLAYERS 5
#define NGRAPHS 8192
#define BN_EPS_C 1e-5f

typedef __attribute__((ext_vector_type(8))) short short8;
typedef __attribute__((ext_vector_type(8))) unsigned short ushort8;
typedef __attribute__((ext_vector_type(4))) float f32x4;

__device__ inline float bf2f(unsigned short u) {
    union { unsigned int i; float f; } c; c.i = ((unsigned int)u) << 16; return c.f;
}
__device__ inline unsigned short f2bf(float f) {
    union { float f; unsigned int i; } c; c.f = f;
    unsigned int x = c.i;
    x += 0x7FFFu + ((x >> 16) & 1u);      // RNE
    return (unsigned short)(x >> 16);
}

// ---------------- fused GIN MLP: Z = maybe_relu(relu(A@W1+b1)@W2+b2) ----------------
// A: [NN][128] bf16 row-major. W1sw/W2sw: pre-swizzled bf16 [(kg*128 + (n^(kg&7)))*8 + (k&7)].
// 128-row tile per block, 256 threads = 4 waves, each wave does 32 rows x 128 cols.
template<int RELU2>
__global__ __launch_bounds__(256, 2) void gin_mlp_kernel(
    const unsigned short* __restrict__ A,
    const unsigned short* __restrict__ W1sw, const unsigned short* __restrict__ W2sw,
    const float* __restrict__ b1, const float* __restrict__ b2,
    unsigned short* __restrict__ Z)
{
    __shared__ unsigned short Abuf[16 * 128 * 8];   // 32 KB
    __shared__ unsigned short Wbuf[16 * 128 * 8];   // 32 KB

    int t = threadIdx.x;
    int r0 = blockIdx.x * 128;
    int lane = t & 63;
    int wv = t >> 6;          // wave 0..3
    int l15 = lane & 15;
    int lg = lane >> 4;       // 0..3

    // stage A (frag layout [kg][m^(kg&7)][8]) + W1 (linear)
#pragma unroll
    for (int it = 0; it < 8; ++it) {
        int flat = it * 256 + t;
        int kg = flat & 15, m = flat >> 4;
        int r = r0 + m;
        ushort8 v;
#pragma unroll
        for (int i = 0; i < 8; ++i) v[i] = 0;
        if (r < NN) v = *(const ushort8*)(A + (size_t)r * DIM + kg * 8);
        *(ushort8*)&Abuf[(kg * 128 + (m ^ (kg & 7))) * 8] = v;
        int idx = flat * 8;
        *(ushort8*)&Wbuf[idx] = *(const ushort8*)(W1sw + idx);
    }
    __syncthreads();

    float b1v[8], b2v[8];
#pragma unroll
    for (int nt = 0; nt < 8; ++nt) { b1v[nt] = b1[nt * 16 + l15]; b2v[nt] = b2[nt * 16 + l15]; }

    f32x4 zero4 = {0.f, 0.f, 0.f, 0.f};
    f32x4 acc[2][8];
#pragma unroll
    for (int mt = 0; mt < 2; ++mt)
#pragma unroll
        for (int nt = 0; nt < 8; ++nt) acc[mt][nt] = zero4;

    // GEMM1
#pragma unroll
    for (int ks = 0; ks < 4; ++ks) {
        int kgp = ks * 4 + lg;
        short8 a0 = *(const short8*)&Abuf[(kgp * 128 + ((wv * 32 + l15) ^ (kgp & 7))) * 8];
        short8 a1 = *(const short8*)&Abuf[(kgp * 128 + ((wv * 32 + 16 + l15) ^ (kgp & 7))) * 8];
#pragma unroll
        for (int nt = 0; nt < 8; ++nt) {
            short8 b = *(const short8*)&Wbuf[(kgp * 128 + ((nt * 16 + l15) ^ (kgp & 7))) * 8];
            acc[0][nt] = __builtin_amdgcn_mfma_f32_16x16x32_bf16(a0, b, acc[0][nt], 0, 0, 0);
            acc[1][nt] = __builtin_amdgcn_mfma_f32_16x16x32_bf16(a1, b, acc[1][nt], 0, 0, 0);
        }
    }
    __syncthreads();

    // C1 -> Abuf (row-major, byte-XOR (r&7)<<4), relu+bias; stage W2
#pragma unroll
    for (int mt = 0; mt < 2; ++mt)
#pragma unroll
        for (int nt = 0; nt < 8; ++nt)
#pragma unroll
            for (int rg = 0; rg < 4; ++rg) {
                int rr = wv * 32 + mt * 16 + lg * 4 + rg;
                int c = nt * 16 + l15;
                float v = fmaxf(acc[mt][nt][rg] + b1v[nt], 0.f);
                unsigned byte = (unsigned)((rr * 128 + c) * 2) ^ (unsigned)((rr & 7) << 4);
                *(unsigned short*)((char*)Abuf + byte) = f2bf(v);
            }
#pragma unroll
    for (int it = 0; it < 8; ++it) {
        int idx = (it * 256 + t) * 8;
        *(ushort8*)&Wbuf[idx] = *(const ushort8*)(W2sw + idx);
    }
    __syncthreads();

    f32x4 acc2[2][8];
#pragma unroll
    for (int mt = 0; mt < 2; ++mt)
#pragma unroll
        for (int nt = 0; nt < 8; ++nt) acc2[mt][nt] = zero4;

    // GEMM2 (A2 row-major XOR reads)
#pragma unroll
    for (int ks = 0; ks < 4; ++ks) {
        int kgp = ks * 4 + lg;
        int m0 = wv * 32 + l15, m1 = m0 + 16;
        unsigned ba0 = (unsigned)(m0 * 256 + kgp * 16) ^ (unsigned)((m0 & 7) << 4);
        unsigned ba1 = (unsigned)(m1 * 256 + kgp * 16) ^ (unsigned)((m1 & 7) << 4);
        short8 a0 = *(const short8*)((char*)Abuf + ba0);
        short8 a1 = *(const short8*)((char*)Abuf + ba1);
#pragma unroll
        for (int nt = 0; nt < 8; ++nt) {
            short8 b = *(const short8*)&Wbuf[(kgp * 128 + ((nt * 16 + l15) ^ (kgp & 7))) * 8];
            acc2[0][nt] = __builtin_amdgcn_mfma_f32_16x16x32_bf16(a0, b, acc2[0][nt], 0, 0, 0);
            acc2[1][nt] = __builtin_amdgcn_mfma_f32_16x16x32_bf16(a1, b, acc2[1][nt], 0, 0, 0);
        }
    }

    // epilogue
#pragma unroll
    for (int mt = 0; mt < 2; ++mt)
#pragma unroll
        for (int nt = 0; nt < 8; ++nt)
#pragma unroll
            for (int rg = 0; rg < 4; ++rg) {
                int rr = wv * 32 + mt * 16 + lg * 4 + rg;
                int r = r0 + rr;
                if (r < NN) {
                    int c = nt * 16 + l15;
                    float v = acc2[mt][nt][rg] + b2v[nt];
                    if (RELU2) v = fmaxf(v, 0.f);
                    Z[(size_t)r * DIM + c] = f2bf(v);
                }
            }
}

// ---------------- weight conversion: fp32 [K][128] -> swizzled bf16 ----------------
__global__ __launch_bounds__(256) void wconv_kernel(
    const float* __restrict__ ini_w1, const float* __restrict__ ini_w2,
    const float* __restrict__ gw1, const float* __restrict__ gw2,
    unsigned short* __restrict__ Wsw)
{
    int id = blockIdx.x * 256 + threadIdx.x;     // 0..16383
    int k = id >> 7, n = id & 127;
    int y = blockIdx.y;
    float v;
    if (y == 0)      v = (k < NFEAT) ? ini_w1[k * DIM + n] : 0.f;
    else if (y == 1) v = ini_w2[k * DIM + n];
    else if (y < 7)  v = gw1[(size_t)(y - 2) * DIM * DIM + k * DIM + n];
    else             v = gw2[(size_t)(y - 7) * DIM * DIM + k * DIM + n];
    int kg = k >> 3;
    Wsw[(size_t)y * 16384 + (size_t)(kg * 128 + (n ^ (kg & 7))) * 8 + (k & 7)] = f2bf(v);
}

// ---------------- x padding: fp32 [NN][78] -> bf16 [NN][128] (zero-pad) ----------------
__global__ __launch_bounds__(256) void xpad_kernel(
    const float* __restrict__ x, unsigned short* __restrict__ xp)
{
    int t = blockIdx.x * 256 + threadIdx.x;      // NN*16 exactly
    int n = t >> 4, j = t & 15;
    ushort8 o;
#pragma unroll
    for (int i = 0; i < 8; ++i) {
        int c = j * 8 + i;
        o[i] = (c < NFEAT) ? f2bf(x[(size_t)n * NFEAT + c]) : (unsigned short)0;
    }
    *(ushort8*)(xp + (size_t)n * DIM + j * 8) = o;
}

// ---------------- CSR build (once per launch) ----------------
__global__ __launch_bounds__(256) void deg_kernel(const int* __restrict__ ei, int* __restrict__ deg)
{
    int e = blockIdx.x * 256 + threadIdx.x;
    if (e >= NE) return;
    atomicAdd(&deg[ei[NE + e]], 1);
}

__global__ __launch_bounds__(256) void scanA_kernel(
    const int* __restrict__ deg, int* __restrict__ cursor, int* __restrict__ partials)
{
    __shared__ int sh[256];
    int i = blockIdx.x * 256 + threadIdx.x;
    int v = (i < NN) ? deg[i] : 0;
    sh[threadIdx.x] = v;
    __syncthreads();
    for (int off = 1; off < 256; off <<= 1) {
        int t2 = (threadIdx.x >= off) ? sh[threadIdx.x - off] : 0;
        __syncthreads();
        sh[threadIdx.x] += t2;
        __syncthreads();
    }
    int incl = sh[threadIdx.x];
    if (i < NN) cursor[i] = incl - v;
    if (threadIdx.x == 255) partials[blockIdx.x] = incl;
}

__global__ __launch_bounds__(1024) void scanB_kernel(int* __restrict__ partials, int nb)
{
    __shared__ int sh[1024];
    int i = threadIdx.x;
    int v = (i < nb) ? partials[i] : 0;
    sh[i] = v;
    __syncthreads();
    for (int off = 1; off < 1024; off <<= 1) {
        int t2 = (i >= off) ? sh[i - off] : 0;
        __syncthreads();
        sh[i] += t2;
        __syncthreads();
    }
    if (i < nb) partials[i] = sh[i] - v;
}

__global__ __launch_bounds__(256) void scanC_kernel(
    int* __restrict__ cursor, const int* __restrict__ partials)
{
    int i = blockIdx.x * 256 + threadIdx.x;
    if (i < NN) cursor[i] += partials[blockIdx.x];
}

__global__ __launch_bounds__(256) void fill_kernel(
    const int* __restrict__ ei, int* __restrict__ cursor, int* __restrict__ csr_src)
{
    int e = blockIdx.x * 256 + threadIdx.x;
    if (e >= NE) return;
    int slot = atomicAdd(&cursor[ei[NE + e]], 1);
    csr_src[slot] = ei[e];
}

// ---------------- gather: agg[n] = h[n] + sum h[nbr] (bf16 in/out, fp32 accum) ----------------
__global__ __launch_bounds__(256) void gather_kernel(
    const unsigned short* __restrict__ h, const int* __restrict__ cursor,
    const int* __restrict__ csr_src, unsigned short* __restrict__ agg)
{
    int t = blockIdx.x * 256 + threadIdx.x;      // NN*16 exactly
    int n = t >> 4, j = t & 15;
    int end = cursor[n];
    int beg = (n == 0) ? 0 : cursor[n - 1];
    ushort8 sv = *(const ushort8*)(h + (size_t)n * DIM + j * 8);
    float a[8];
#pragma unroll
    for (int i = 0; i < 8; ++i) a[i] = bf2f(sv[i]);
    for (int e = beg; e < end; ++e) {
        int s = csr_src[e];
        ushort8 v = *(const ushort8*)(h + (size_t)s * DIM + j * 8);
#pragma unroll
        for (int i = 0; i < 8; ++i) a[i] += bf2f(v[i]);
    }
    ushort8 o;
#pragma unroll
    for (int i = 0; i < 8; ++i) o[i] = f2bf(a[i]);
    *(ushort8*)(agg + (size_t)n * DIM + j * 8) = o;
}

// ---------------- stats: column sum/sumsq over bf16 z ----------------
__global__ __launch_bounds__(256) void stats_kernel(
    const unsigned short* __restrict__ z, float* __restrict__ stats)
{
    int d = threadIdx.x & (DIM - 1);
    int r = threadIdx.x >> 7;
    int stride = gridDim.x * 2;
    float s = 0.f, sq = 0.f;
    for (int n = blockIdx.x * 2 + r; n < NN; n += stride) {
        float v = bf2f(z[(size_t)n * DIM + d]);
        s += v;
        sq += v * v;
    }
    atomicAdd(&stats[d], s);
    atomicAdd(&stats[DIM + d], sq);
}

__global__ void finalize_kernel(
    const float* __restrict__ stats, const float* __restrict__ gamma,
    const float* __restrict__ beta, float* __restrict__ affine)
{
    int d = threadIdx.x;
    float mean = stats[d] * (1.0f / NN);
    float var = stats[DIM + d] * (1.0f / NN) - mean * mean;
    float a = gamma[d] * rsqrtf(var + BN_EPS_C);
    affine[d] = a;
    affine[DIM + d] = beta[d] - mean * a;
}

// ---------------- fused BN-apply + pool (bf16 z in, bf16 h out) ----------------
#define BP_NPB 256
__global__ __launch_bounds__(128) void bnpool_kernel(
    const unsigned short* __restrict__ z, const float* __restrict__ affine,
    const int* __restrict__ batch, const float* __restrict__ lcw, int l,
    const float* __restrict__ lcb_p, int add_lcb, int write_h,
    unsigned short* __restrict__ h, float* __restrict__ out)
{
    int d = threadIdx.x;
    int n0 = blockIdx.x * BP_NPB;
    int nend = n0 + BP_NPB;
    if (nend > NN) nend = NN;
    float a = affine[d];
    float c = affine[DIM + d];
    float w = lcw[l];
    float lcb = add_lcb ? *lcb_p : 0.f;
    float acc = 0.f;
    int cur = -1;
    for (int n = n0; n < nend; ++n) {
        float zv = bf2f(z[(size_t)n * DIM + d]);
        float hv = fmaf(a, zv, c);
        if (write_h) h[(size_t)n * DIM + d] = f2bf(hv);
        int g = batch[n];
        if (g != cur) {
            if (cur >= 0) atomicAdd(&out[(size_t)cur * DIM + d], acc);
            cur = g;
            acc = 0.f;
        }
        acc = fmaf(w, hv, acc) + lcb;
    }
    if (cur >= 0) atomicAdd(&out[(size_t)cur * DIM + d], acc);
}

extern "C" void kernel_launch(void* const* d_in, const int* in_sizes, int n_in,
                              void* d_out, int out_size, void* d_ws, size_t ws_size,
                              hipStream_t stream)
{
    const float* x      = (const float*)d_in[0];
    const int*   ei     = (const int*)d_in[1];
    const int*   batch  = (const int*)d_in[2];
    const float* ini_w1 = (const float*)d_in[4];
    const float* ini_b1 = (const float*)d_in[5];
    const float* ini_w2 = (const float*)d_in[6];
    const float* ini_b2 = (const float*)d_in[7];
    const float* gw1    = (const float*)d_in[8];
    const float* gb1    = (const float*)d_in[9];
    const float* gw2    = (const float*)d_in[10];
    const float* gb2    = (const float*)d_in[11];
    const float* gamma  = (const float*)d_in[12];
    const float* beta   = (const float*)d_in[13];
    const float* lcw    = (const float*)d_in[14];
    const float* lcb    = (const float*)d_in[15];
    float* out = (float*)d_out;

    size_t NHs = (size_t)NN * DIM;                       // ushort count per node buffer
    unsigned short* h   = (unsigned short*)d_ws;
    unsigned short* agg = h + NHs;
    unsigned short* xp  = agg + NHs;
    unsigned short* Wsw = xp + NHs;                      // 12 * 16384 ushorts
    float* stats  = (float*)(Wsw + 12 * 16384);
    float* affine = stats + NLAYERS * 256;
    int* deg      = (int*)(affine + NLAYERS * 256);
    int* cursor   = deg + NN;
    int* csr_src  = cursor + NN;
    int* partials = csr_src + NE;
    size_t need = (size_t)((char*)(partials + 1024) - (char*)d_ws);

    hipMemsetAsync(out, 0, (size_t)NGRAPHS * DIM * sizeof(float), stream);
    if (ws_size < need) return;   // diagnostic: zero output signals ws shortfall

    hipMemsetAsync(stats, 0, NLAYERS * 256 * sizeof(float), stream);
    hipMemsetAsync(deg, 0, NN * sizeof(int), stream);

    int nb = (NN + 255) / 256;     // 782
    int eb = (NE + 255) / 256;

    deg_kernel<<<eb, 256, 0, stream>>>(ei, deg);
    scanA_kernel<<<nb, 256, 0, stream>>>(deg, cursor, partials);
    scanB_kernel<<<1, 1024, 0, stream>>>(partials, nb);
    scanC_kernel<<<nb, 256, 0, stream>>>(cursor, partials);
    fill_kernel<<<eb, 256, 0, stream>>>(ei, cursor, csr_src);

    xpad_kernel<<<NN * 16 / 256, 256, 0, stream>>>(x, xp);
    wconv_kernel<<<dim3(64, 12), 256, 0, stream>>>(ini_w1, ini_w2, gw1, gw2, Wsw);

    int gin_blocks = (NN + 127) / 128;   // 1563
    int bp_blocks = (NN + BP_NPB - 1) / BP_NPB;

    // ini_embed: h = relu(xp@W1+b1)@W2+b2   (no relu on output)
    gin_mlp_kernel<0><<<gin_blocks, 256, 0, stream>>>(
        xp, Wsw, Wsw + 16384, ini_b1, ini_b2, h);

    for (int l = 0; l < NLAYERS; ++l) {
        gather_kernel<<<NN * 16 / 256, 256, 0, stream>>>(h, cursor, csr_src, agg);
        // z = relu(relu(agg@W1+b1)@W2+b2), in-place agg (block reads own rows before writing)
        gin_mlp_kernel<1><<<gin_blocks, 256, 0, stream>>>(
            agg, Wsw + (size_t)(2 + l) * 16384, Wsw + (size_t)(7 + l) * 16384,
            gb1 + l * DIM, gb2 + l * DIM, agg);
        stats_kernel<<<1024, 256, 0, stream>>>(agg, stats + l * 256);
        finalize_kernel<<<1, 128, 0, stream>>>(
            stats + l * 256, gamma + l * DIM, beta + l * DIM, affine + l * 256);
        bnpool_kernel<<<bp_blocks, 128, 0, stream>>>(
            agg, affine + l * 256, batch, lcw, l, lcb,
            (l == 0) ? 1 : 0, (l == NLAYERS - 1) ? 0 : 1, h, out);
    }
}

// Round 6
// 781.726 us; speedup vs baseline: 10.6535x; 1.6397x over previous
//
#include <hip/hip_runtime.h>

#define NN 200000
#define NE 400000
#define NFEAT 78
#define DIM 128
#define NLAYERS 5
#define NGRAPHS 8192
#define BN_EPS_C 1e-5f
#define NSLOT 32

typedef __attribute__((ext_vector_type(8))) short short8;
typedef __attribute__((ext_vector_type(8))) unsigned short ushort8;
typedef __attribute__((ext_vector_type(4))) float f32x4;

__device__ inline float bf2f(unsigned short u) {
    union { unsigned int i; float f; } c; c.i = ((unsigned int)u) << 16; return c.f;
}
__device__ inline unsigned short f2bf(float f) {
    union { float f; unsigned int i; } c; c.f = f;
    unsigned int x = c.i;
    x += 0x7FFFu + ((x >> 16) & 1u);      // RNE
    return (unsigned short)(x >> 16);
}

// ---------------- fused GIN MLP: Z = maybe_relu(relu(A@W1+b1)@W2+b2) ----------------
// A: [NN][128] bf16 row-major. W1sw/W2sw: pre-swizzled bf16 [(kg*128 + (n^(kg&7)))*8 + (k&7)].
// 128-row tile per block, 256 threads = 4 waves. STATS: accumulate col sum/sumsq of the
// fp32 outputs into stats_base[(blockIdx&31)*256 + {d | 128+d}] (32-way replicated slots).
template<int RELU2, int STATS>
__global__ __launch_bounds__(256, 2) void gin_mlp_kernel(
    const unsigned short* __restrict__ A,
    const unsigned short* __restrict__ W1sw, const unsigned short* __restrict__ W2sw,
    const float* __restrict__ b1, const float* __restrict__ b2,
    unsigned short* __restrict__ Z, float* __restrict__ stats_base)
{
    __shared__ unsigned short Abuf[16 * 128 * 8];   // 32 KB
    __shared__ unsigned short Wbuf[16 * 128 * 8];   // 32 KB
    __shared__ float sst[256];                      // 1 KB (stats reduce)

    int t = threadIdx.x;
    int r0 = blockIdx.x * 128;
    int lane = t & 63;
    int wv = t >> 6;          // wave 0..3
    int l15 = lane & 15;
    int lg = lane >> 4;       // 0..3

    // stage A (frag layout [kg][m^(kg&7)][8]) + W1 (linear)
#pragma unroll
    for (int it = 0; it < 8; ++it) {
        int flat = it * 256 + t;
        int kg = flat & 15, m = flat >> 4;
        int r = r0 + m;
        ushort8 v;
#pragma unroll
        for (int i = 0; i < 8; ++i) v[i] = 0;
        if (r < NN) v = *(const ushort8*)(A + (size_t)r * DIM + kg * 8);
        *(ushort8*)&Abuf[(kg * 128 + (m ^ (kg & 7))) * 8] = v;
        int idx = flat * 8;
        *(ushort8*)&Wbuf[idx] = *(const ushort8*)(W1sw + idx);
    }
    __syncthreads();

    float b1v[8], b2v[8];
#pragma unroll
    for (int nt = 0; nt < 8; ++nt) { b1v[nt] = b1[nt * 16 + l15]; b2v[nt] = b2[nt * 16 + l15]; }

    f32x4 zero4 = {0.f, 0.f, 0.f, 0.f};
    f32x4 acc[2][8];
#pragma unroll
    for (int mt = 0; mt < 2; ++mt)
#pragma unroll
        for (int nt = 0; nt < 8; ++nt) acc[mt][nt] = zero4;

    // GEMM1
#pragma unroll
    for (int ks = 0; ks < 4; ++ks) {
        int kgp = ks * 4 + lg;
        short8 a0 = *(const short8*)&Abuf[(kgp * 128 + ((wv * 32 + l15) ^ (kgp & 7))) * 8];
        short8 a1 = *(const short8*)&Abuf[(kgp * 128 + ((wv * 32 + 16 + l15) ^ (kgp & 7))) * 8];
#pragma unroll
        for (int nt = 0; nt < 8; ++nt) {
            short8 b = *(const short8*)&Wbuf[(kgp * 128 + ((nt * 16 + l15) ^ (kgp & 7))) * 8];
            acc[0][nt] = __builtin_amdgcn_mfma_f32_16x16x32_bf16(a0, b, acc[0][nt], 0, 0, 0);
            acc[1][nt] = __builtin_amdgcn_mfma_f32_16x16x32_bf16(a1, b, acc[1][nt], 0, 0, 0);
        }
    }
    __syncthreads();

    // C1 -> Abuf (row-major, byte-XOR (r&7)<<4), relu+bias; stage W2
#pragma unroll
    for (int mt = 0; mt < 2; ++mt)
#pragma unroll
        for (int nt = 0; nt < 8; ++nt)
#pragma unroll
            for (int rg = 0; rg < 4; ++rg) {
                int rr = wv * 32 + mt * 16 + lg * 4 + rg;
                int c = nt * 16 + l15;
                float v = fmaxf(acc[mt][nt][rg] + b1v[nt], 0.f);
                unsigned byte = (unsigned)((rr * 128 + c) * 2) ^ (unsigned)((rr & 7) << 4);
                *(unsigned short*)((char*)Abuf + byte) = f2bf(v);
            }
#pragma unroll
    for (int it = 0; it < 8; ++it) {
        int idx = (it * 256 + t) * 8;
        *(ushort8*)&Wbuf[idx] = *(const ushort8*)(W2sw + idx);
    }
    __syncthreads();

    f32x4 acc2[2][8];
#pragma unroll
    for (int mt = 0; mt < 2; ++mt)
#pragma unroll
        for (int nt = 0; nt < 8; ++nt) acc2[mt][nt] = zero4;

    // GEMM2 (A2 row-major XOR reads)
#pragma unroll
    for (int ks = 0; ks < 4; ++ks) {
        int kgp = ks * 4 + lg;
        int m0 = wv * 32 + l15, m1 = m0 + 16;
        unsigned ba0 = (unsigned)(m0 * 256 + kgp * 16) ^ (unsigned)((m0 & 7) << 4);
        unsigned ba1 = (unsigned)(m1 * 256 + kgp * 16) ^ (unsigned)((m1 & 7) << 4);
        short8 a0 = *(const short8*)((char*)Abuf + ba0);
        short8 a1 = *(const short8*)((char*)Abuf + ba1);
#pragma unroll
        for (int nt = 0; nt < 8; ++nt) {
            short8 b = *(const short8*)&Wbuf[(kgp * 128 + ((nt * 16 + l15) ^ (kgp & 7))) * 8];
            acc2[0][nt] = __builtin_amdgcn_mfma_f32_16x16x32_bf16(a0, b, acc2[0][nt], 0, 0, 0);
            acc2[1][nt] = __builtin_amdgcn_mfma_f32_16x16x32_bf16(a1, b, acc2[1][nt], 0, 0, 0);
        }
    }

    if (STATS) {
        sst[t] = 0.f;
        __syncthreads();
    }

    // epilogue (+ per-block stats reduce)
#pragma unroll
    for (int nt = 0; nt < 8; ++nt) {
        float sum8 = 0.f, sq8 = 0.f;
        int c = nt * 16 + l15;
#pragma unroll
        for (int mt = 0; mt < 2; ++mt)
#pragma unroll
            for (int rg = 0; rg < 4; ++rg) {
                int rr = wv * 32 + mt * 16 + lg * 4 + rg;
                int r = r0 + rr;
                if (r < NN) {
                    float v = acc2[mt][nt][rg] + b2v[nt];
                    if (RELU2) v = fmaxf(v, 0.f);
                    Z[(size_t)r * DIM + c] = f2bf(v);
                    if (STATS) { sum8 += v; sq8 += v * v; }
                }
            }
        if (STATS) {
            atomicAdd(&sst[c], sum8);
            atomicAdd(&sst[128 + c], sq8);
        }
    }
    if (STATS) {
        __syncthreads();
        atomicAdd(&stats_base[(blockIdx.x & (NSLOT - 1)) * 256 + t], sst[t]);
    }
}

// ---------------- weight conversion: fp32 [K][128] -> swizzled bf16 ----------------
__global__ __launch_bounds__(256) void wconv_kernel(
    const float* __restrict__ ini_w1, const float* __restrict__ ini_w2,
    const float* __restrict__ gw1, const float* __restrict__ gw2,
    unsigned short* __restrict__ Wsw)
{
    int id = blockIdx.x * 256 + threadIdx.x;     // 0..16383
    int k = id >> 7, n = id & 127;
    int y = blockIdx.y;
    float v;
    if (y == 0)      v = (k < NFEAT) ? ini_w1[k * DIM + n] : 0.f;
    else if (y == 1) v = ini_w2[k * DIM + n];
    else if (y < 7)  v = gw1[(size_t)(y - 2) * DIM * DIM + k * DIM + n];
    else             v = gw2[(size_t)(y - 7) * DIM * DIM + k * DIM + n];
    int kg = k >> 3;
    Wsw[(size_t)y * 16384 + (size_t)(kg * 128 + (n ^ (kg & 7))) * 8 + (k & 7)] = f2bf(v);
}

// ---------------- x padding: fp32 [NN][78] -> bf16 [NN][128] (zero-pad) ----------------
__global__ __launch_bounds__(256) void xpad_kernel(
    const float* __restrict__ x, unsigned short* __restrict__ xp)
{
    int t = blockIdx.x * 256 + threadIdx.x;      // NN*16 exactly
    int n = t >> 4, j = t & 15;
    ushort8 o;
#pragma unroll
    for (int i = 0; i < 8; ++i) {
        int c = j * 8 + i;
        o[i] = (c < NFEAT) ? f2bf(x[(size_t)n * NFEAT + c]) : (unsigned short)0;
    }
    *(ushort8*)(xp + (size_t)n * DIM + j * 8) = o;
}

// ---------------- CSR build (once per launch) ----------------
__global__ __launch_bounds__(256) void deg_kernel(const int* __restrict__ ei, int* __restrict__ deg)
{
    int e = blockIdx.x * 256 + threadIdx.x;
    if (e >= NE) return;
    atomicAdd(&deg[ei[NE + e]], 1);
}

__global__ __launch_bounds__(256) void scanA_kernel(
    const int* __restrict__ deg, int* __restrict__ cursor, int* __restrict__ partials)
{
    __shared__ int sh[256];
    int i = blockIdx.x * 256 + threadIdx.x;
    int v = (i < NN) ? deg[i] : 0;
    sh[threadIdx.x] = v;
    __syncthreads();
    for (int off = 1; off < 256; off <<= 1) {
        int t2 = (threadIdx.x >= off) ? sh[threadIdx.x - off] : 0;
        __syncthreads();
        sh[threadIdx.x] += t2;
        __syncthreads();
    }
    int incl = sh[threadIdx.x];
    if (i < NN) cursor[i] = incl - v;
    if (threadIdx.x == 255) partials[blockIdx.x] = incl;
}

__global__ __launch_bounds__(1024) void scanB_kernel(int* __restrict__ partials, int nb)
{
    __shared__ int sh[1024];
    int i = threadIdx.x;
    int v = (i < nb) ? partials[i] : 0;
    sh[i] = v;
    __syncthreads();
    for (int off = 1; off < 1024; off <<= 1) {
        int t2 = (i >= off) ? sh[i - off] : 0;
        __syncthreads();
        sh[i] += t2;
        __syncthreads();
    }
    if (i < nb) partials[i] = sh[i] - v;
}

__global__ __launch_bounds__(256) void scanC_kernel(
    int* __restrict__ cursor, const int* __restrict__ partials)
{
    int i = blockIdx.x * 256 + threadIdx.x;
    if (i < NN) cursor[i] += partials[blockIdx.x];
}

__global__ __launch_bounds__(256) void fill_kernel(
    const int* __restrict__ ei, int* __restrict__ cursor, int* __restrict__ csr_src)
{
    int e = blockIdx.x * 256 + threadIdx.x;
    if (e >= NE) return;
    int slot = atomicAdd(&cursor[ei[NE + e]], 1);
    csr_src[slot] = ei[e];
}

// graph_ptr[g] = first node index with batch >= g (batch sorted); gptr[NGRAPHS] = NN
__global__ __launch_bounds__(256) void gptr_kernel(
    const int* __restrict__ batch, int* __restrict__ gptr)
{
    int n = blockIdx.x * 256 + threadIdx.x;
    if (n > NN) return;
    int b1 = (n < NN) ? batch[n] : NGRAPHS;
    int b0 = (n == 0) ? -1 : batch[n - 1];
    for (int g = b0 + 1; g <= b1; ++g) gptr[g] = n;
}

__global__ void ident_kernel(float* __restrict__ aff)
{
    int d = threadIdx.x;
    aff[d] = 1.f;
    aff[DIM + d] = 0.f;
}

// ---------------- affine-fused gather ----------------
// agg[n] = a ⊙ (z[n] + sum_nbr z) + (deg+1)·c   (h never materialized)
__global__ __launch_bounds__(256) void gather_kernel(
    const unsigned short* __restrict__ z, const int* __restrict__ cursor,
    const int* __restrict__ csr_src, const float* __restrict__ aff,
    unsigned short* __restrict__ agg)
{
    int t = blockIdx.x * 256 + threadIdx.x;      // NN*16 exactly
    int n = t >> 4, j = t & 15;
    int end = cursor[n];
    int beg = (n == 0) ? 0 : cursor[n - 1];
    ushort8 sv = *(const ushort8*)(z + (size_t)n * DIM + j * 8);
    float a[8];
#pragma unroll
    for (int i = 0; i < 8; ++i) a[i] = bf2f(sv[i]);
    for (int e = beg; e < end; ++e) {
        int s = csr_src[e];
        ushort8 v = *(const ushort8*)(z + (size_t)s * DIM + j * 8);
#pragma unroll
        for (int i = 0; i < 8; ++i) a[i] += bf2f(v[i]);
    }
    float cnt = (float)(end - beg + 1);
    ushort8 o;
#pragma unroll
    for (int i = 0; i < 8; ++i) {
        float av = aff[j * 8 + i];
        float cv = aff[DIM + j * 8 + i];
        o[i] = f2bf(fmaf(av, a[i], cnt * cv));
    }
    *(ushort8*)(agg + (size_t)n * DIM + j * 8) = o;
}

// ---------------- per-graph pool: out[g] += lcw*(a⊙segsum(z) + cnt*c) (+ cnt*lcb) ----------------
__global__ __launch_bounds__(128) void pool_kernel(
    const unsigned short* __restrict__ z, const int* __restrict__ gptr,
    const float* __restrict__ aff, const float* __restrict__ lcw, int l,
    const float* __restrict__ lcb_p, int add_lcb, float* __restrict__ out)
{
    int g = blockIdx.x;
    int d = threadIdx.x;
    int p0 = gptr[g], p1 = gptr[g + 1];
    float S = 0.f;
    for (int n = p0; n < p1; ++n) S += bf2f(z[(size_t)n * DIM + d]);
    float w = lcw[l];
    float cnt = (float)(p1 - p0);
    float v = w * fmaf(aff[d], S, cnt * aff[DIM + d]);
    if (add_lcb) v = fmaf(cnt, *lcb_p, v);
    out[(size_t)g * DIM + d] += v;
}

// per-layer: affine[d] = gamma*rsqrt(var+eps); affine[128+d] = beta - mean*a
__global__ void finalize_kernel(
    const float* __restrict__ slots, const float* __restrict__ gamma,
    const float* __restrict__ beta, float* __restrict__ aff)
{
    int d = threadIdx.x;
    float s = 0.f, sq = 0.f;
    for (int i = 0; i < NSLOT; ++i) {
        s  += slots[i * 256 + d];
        sq += slots[i * 256 + 128 + d];
    }
    float mean = s * (1.0f / NN);
    float var = sq * (1.0f / NN) - mean * mean;
    float a = gamma[d] * rsqrtf(var + BN_EPS_C);
    aff[d] = a;
    aff[DIM + d] = beta[d] - mean * a;
}

extern "C" void kernel_launch(void* const* d_in, const int* in_sizes, int n_in,
                              void* d_out, int out_size, void* d_ws, size_t ws_size,
                              hipStream_t stream)
{
    const float* x      = (const float*)d_in[0];
    const int*   ei     = (const int*)d_in[1];
    const int*   batch  = (const int*)d_in[2];
    const float* ini_w1 = (const float*)d_in[4];
    const float* ini_b1 = (const float*)d_in[5];
    const float* ini_w2 = (const float*)d_in[6];
    const float* ini_b2 = (const float*)d_in[7];
    const float* gw1    = (const float*)d_in[8];
    const float* gb1    = (const float*)d_in[9];
    const float* gw2    = (const float*)d_in[10];
    const float* gb2    = (const float*)d_in[11];
    const float* gamma  = (const float*)d_in[12];
    const float* beta   = (const float*)d_in[13];
    const float* lcw    = (const float*)d_in[14];
    const float* lcb    = (const float*)d_in[15];
    float* out = (float*)d_out;

    size_t NHs = (size_t)NN * DIM;                       // ushort count per node buffer
    unsigned short* bufA = (unsigned short*)d_ws;
    unsigned short* bufB = bufA + NHs;                   // also holds padded x pre-ini
    unsigned short* Wsw  = bufB + NHs;                   // 12 * 16384 ushorts
    float* stats  = (float*)(Wsw + 12 * 16384);          // NLAYERS * NSLOT * 256
    float* affine = stats + (size_t)NLAYERS * NSLOT * 256; // (NLAYERS+1) * 256
    int* deg      = (int*)(affine + (NLAYERS + 1) * 256);
    int* cursor   = deg + NN;
    int* csr_src  = cursor + NN;
    int* partials = csr_src + NE;
    int* gptr     = partials + 1024;
    size_t need = (size_t)((char*)(gptr + NGRAPHS + 1) - (char*)d_ws);

    hipMemsetAsync(out, 0, (size_t)NGRAPHS * DIM * sizeof(float), stream);
    if (ws_size < need) return;   // diagnostic: zero output signals ws shortfall

    hipMemsetAsync(stats, 0, (size_t)NLAYERS * NSLOT * 256 * sizeof(float), stream);
    hipMemsetAsync(deg, 0, NN * sizeof(int), stream);

    int nb = (NN + 255) / 256;     // 782
    int eb = (NE + 255) / 256;

    deg_kernel<<<eb, 256, 0, stream>>>(ei, deg);
    scanA_kernel<<<nb, 256, 0, stream>>>(deg, cursor, partials);
    scanB_kernel<<<1, 1024, 0, stream>>>(partials, nb);
    scanC_kernel<<<nb, 256, 0, stream>>>(cursor, partials);
    fill_kernel<<<eb, 256, 0, stream>>>(ei, cursor, csr_src);
    gptr_kernel<<<(NN + 256) / 256 + 1, 256, 0, stream>>>(batch, gptr);
    ident_kernel<<<1, 128, 0, stream>>>(affine);

    xpad_kernel<<<NN * 16 / 256, 256, 0, stream>>>(x, bufB);
    wconv_kernel<<<dim3(64, 12), 256, 0, stream>>>(ini_w1, ini_w2, gw1, gw2, Wsw);

    int gin_blocks = (NN + 127) / 128;   // 1563

    // ini_embed: bufA = relu(xp@W1+b1)@W2+b2 (no relu, no stats)
    gin_mlp_kernel<0, 0><<<gin_blocks, 256, 0, stream>>>(
        bufB, Wsw, Wsw + 16384, ini_b1, ini_b2, bufA, nullptr);

    unsigned short* prev = bufA;
    for (int l = 0; l < NLAYERS; ++l) {
        unsigned short* nxt = (prev == bufA) ? bufB : bufA;
        // nxt = a_{l-1} ⊙ (z_prev + Σ z_prev[nbr]) + (deg+1)·c_{l-1}
        gather_kernel<<<NN * 16 / 256, 256, 0, stream>>>(
            prev, cursor, csr_src, affine + (size_t)l * 256, nxt);
        // nxt = relu(relu(nxt@W1+b1)@W2+b2), in-place; stats fused
        gin_mlp_kernel<1, 1><<<gin_blocks, 256, 0, stream>>>(
            nxt, Wsw + (size_t)(2 + l) * 16384, Wsw + (size_t)(7 + l) * 16384,
            gb1 + l * DIM, gb2 + l * DIM, nxt, stats + (size_t)l * NSLOT * 256);
        finalize_kernel<<<1, 128, 0, stream>>>(
            stats + (size_t)l * NSLOT * 256, gamma + l * DIM, beta + l * DIM,
            affine + (size_t)(l + 1) * 256);
        // out += lcw[l]*(a_l ⊙ segsum(z_l) + cnt*c_l) (+ cnt*lcb on l==0)
        pool_kernel<<<NGRAPHS, 128, 0, stream>>>(
            nxt, gptr, affine + (size_t)(l + 1) * 256, lcw, l, lcb,
            (l == 0) ? 1 : 0, out);
        prev = nxt;
    }
}

// Round 7
// 754.493 us; speedup vs baseline: 11.0381x; 1.0361x over previous
//
#include <hip/hip_runtime.h>

#define NN 200000
#define NE 400000
#define NFEAT 78
#define DIM 128
#define NLAYERS 5
#define NGRAPHS 8192
#define BN_EPS_C 1e-5f
#define NSLOT 32

typedef __attribute__((ext_vector_type(8))) short short8;
typedef __attribute__((ext_vector_type(8))) unsigned short ushort8;
typedef __attribute__((ext_vector_type(4))) float f32x4;

__device__ inline float bf2f(unsigned short u) {
    union { unsigned int i; float f; } c; c.i = ((unsigned int)u) << 16; return c.f;
}
__device__ inline unsigned short f2bf(float f) {
    union { float f; unsigned int i; } c; c.f = f;
    unsigned int x = c.i;
    x += 0x7FFFu + ((x >> 16) & 1u);      // RNE
    return (unsigned short)(x >> 16);
}

// ---------------- fused GIN MLP: Z = maybe_relu(relu(A@W1+b1)@W2+b2) ----------------
// A: [NN][128] bf16 row-major, fragments loaded DIRECTLY from global (wave-private rows).
// W1d/W2d: fragment-direct bf16 [(kg*128 + n)*8 + (k&7)] — B-fragments loaded directly
// from global (32 KB, L2-hot). Only the C1 intermediate goes through LDS (32 KB,
// row-major + byte-XOR (r&7)<<4). Each wave writes/reads only its own 32 rows of C1
// => NO barriers anywhere. 128-row tile per block, 256 threads = 4 waves.
template<int RELU2, int STATS>
__global__ __launch_bounds__(256, 4) void gin_mlp_kernel(
    const unsigned short* __restrict__ A,
    const unsigned short* __restrict__ W1d, const unsigned short* __restrict__ W2d,
    const float* __restrict__ b1, const float* __restrict__ b2,
    unsigned short* __restrict__ Z, float* __restrict__ stats_base)
{
    __shared__ unsigned short C1[128 * 128];        // 32 KB

    int t = threadIdx.x;
    int r0 = blockIdx.x * 128;
    int lane = t & 63;
    int wv = t >> 6;          // wave 0..3
    int l15 = lane & 15;
    int lg = lane >> 4;       // 0..3

    float b1v[8], b2v[8];
#pragma unroll
    for (int nt = 0; nt < 8; ++nt) { b1v[nt] = b1[nt * 16 + l15]; b2v[nt] = b2[nt * 16 + l15]; }

    // A-fragment source rows (clamped; OOB rows produce garbage that is never stored)
    int ra0 = r0 + wv * 32 + l15;       if (ra0 > NN - 1) ra0 = NN - 1;
    int ra1 = r0 + wv * 32 + 16 + l15;  if (ra1 > NN - 1) ra1 = NN - 1;
    const unsigned short* __restrict__ Arow0 = A + (size_t)ra0 * DIM;
    const unsigned short* __restrict__ Arow1 = A + (size_t)ra1 * DIM;

    f32x4 zero4 = {0.f, 0.f, 0.f, 0.f};
    f32x4 acc[2][8];
#pragma unroll
    for (int mt = 0; mt < 2; ++mt)
#pragma unroll
        for (int nt = 0; nt < 8; ++nt) acc[mt][nt] = zero4;

    // GEMM1: A-frags + B-frags straight from global
#pragma unroll
    for (int ks = 0; ks < 4; ++ks) {
        int kgp = ks * 4 + lg;
        short8 a0 = *(const short8*)(Arow0 + kgp * 8);
        short8 a1 = *(const short8*)(Arow1 + kgp * 8);
#pragma unroll
        for (int nt = 0; nt < 8; ++nt) {
            short8 b = *(const short8*)(W1d + (size_t)(kgp * 128 + nt * 16 + l15) * 8);
            acc[0][nt] = __builtin_amdgcn_mfma_f32_16x16x32_bf16(a0, b, acc[0][nt], 0, 0, 0);
            acc[1][nt] = __builtin_amdgcn_mfma_f32_16x16x32_bf16(a1, b, acc[1][nt], 0, 0, 0);
        }
    }

    // C1 -> LDS (row-major, byte-XOR (r&7)<<4), relu+bias. Wave-private rows, no sync.
#pragma unroll
    for (int mt = 0; mt < 2; ++mt)
#pragma unroll
        for (int nt = 0; nt < 8; ++nt)
#pragma unroll
            for (int rg = 0; rg < 4; ++rg) {
                int rr = wv * 32 + mt * 16 + lg * 4 + rg;
                int c = nt * 16 + l15;
                float v = fmaxf(acc[mt][nt][rg] + b1v[nt], 0.f);
                unsigned byte = (unsigned)((rr * 128 + c) * 2) ^ (unsigned)((rr & 7) << 4);
                *(unsigned short*)((char*)C1 + byte) = f2bf(v);
            }

    f32x4 acc2[2][8];
#pragma unroll
    for (int mt = 0; mt < 2; ++mt)
#pragma unroll
        for (int nt = 0; nt < 8; ++nt) acc2[mt][nt] = zero4;

    // GEMM2: A-frags from LDS (XOR reads, own rows), B-frags from global
#pragma unroll
    for (int ks = 0; ks < 4; ++ks) {
        int kgp = ks * 4 + lg;
        int m0 = wv * 32 + l15, m1 = m0 + 16;
        unsigned ba0 = (unsigned)(m0 * 256 + kgp * 16) ^ (unsigned)((m0 & 7) << 4);
        unsigned ba1 = (unsigned)(m1 * 256 + kgp * 16) ^ (unsigned)((m1 & 7) << 4);
        short8 a0 = *(const short8*)((char*)C1 + ba0);
        short8 a1 = *(const short8*)((char*)C1 + ba1);
#pragma unroll
        for (int nt = 0; nt < 8; ++nt) {
            short8 b = *(const short8*)(W2d + (size_t)(kgp * 128 + nt * 16 + l15) * 8);
            acc2[0][nt] = __builtin_amdgcn_mfma_f32_16x16x32_bf16(a0, b, acc2[0][nt], 0, 0, 0);
            acc2[1][nt] = __builtin_amdgcn_mfma_f32_16x16x32_bf16(a1, b, acc2[1][nt], 0, 0, 0);
        }
    }

    // epilogue: store Z; stats via cross-lg shfl reduce + replicated global atomics
#pragma unroll
    for (int nt = 0; nt < 8; ++nt) {
        float sum8 = 0.f, sq8 = 0.f;
        int c = nt * 16 + l15;
#pragma unroll
        for (int mt = 0; mt < 2; ++mt)
#pragma unroll
            for (int rg = 0; rg < 4; ++rg) {
                int rr = wv * 32 + mt * 16 + lg * 4 + rg;
                int r = r0 + rr;
                if (r < NN) {
                    float v = acc2[mt][nt][rg] + b2v[nt];
                    if (RELU2) v = fmaxf(v, 0.f);
                    Z[(size_t)r * DIM + c] = f2bf(v);
                    if (STATS) { sum8 += v; sq8 += v * v; }
                }
            }
        if (STATS) {
            sum8 += __shfl_xor(sum8, 16); sum8 += __shfl_xor(sum8, 32);
            sq8  += __shfl_xor(sq8, 16);  sq8  += __shfl_xor(sq8, 32);
            if (lg == 0) {
                float* sb = stats_base + (size_t)(blockIdx.x & (NSLOT - 1)) * 256;
                atomicAdd(&sb[c], sum8);
                atomicAdd(&sb[128 + c], sq8);
            }
        }
    }
}

// ---------------- weight conversion: fp32 [K][128] -> fragment-direct bf16 ----------------
__global__ __launch_bounds__(256) void wconv_kernel(
    const float* __restrict__ ini_w1, const float* __restrict__ ini_w2,
    const float* __restrict__ gw1, const float* __restrict__ gw2,
    unsigned short* __restrict__ Wd)
{
    int id = blockIdx.x * 256 + threadIdx.x;     // 0..16383
    int k = id >> 7, n = id & 127;
    int y = blockIdx.y;
    float v;
    if (y == 0)      v = (k < NFEAT) ? ini_w1[k * DIM + n] : 0.f;
    else if (y == 1) v = ini_w2[k * DIM + n];
    else if (y < 7)  v = gw1[(size_t)(y - 2) * DIM * DIM + k * DIM + n];
    else             v = gw2[(size_t)(y - 7) * DIM * DIM + k * DIM + n];
    int kg = k >> 3;
    Wd[(size_t)y * 16384 + (size_t)(kg * 128 + n) * 8 + (k & 7)] = f2bf(v);
}

// ---------------- x padding: fp32 [NN][78] -> bf16 [NN][128] (zero-pad) ----------------
__global__ __launch_bounds__(256) void xpad_kernel(
    const float* __restrict__ x, unsigned short* __restrict__ xp)
{
    int t = blockIdx.x * 256 + threadIdx.x;      // NN*16 exactly
    int n = t >> 4, j = t & 15;
    ushort8 o;
#pragma unroll
    for (int i = 0; i < 8; ++i) {
        int c = j * 8 + i;
        o[i] = (c < NFEAT) ? f2bf(x[(size_t)n * NFEAT + c]) : (unsigned short)0;
    }
    *(ushort8*)(xp + (size_t)n * DIM + j * 8) = o;
}

// ---------------- CSR build (once per launch) ----------------
__global__ __launch_bounds__(256) void deg_kernel(const int* __restrict__ ei, int* __restrict__ deg)
{
    int e = blockIdx.x * 256 + threadIdx.x;
    if (e >= NE) return;
    atomicAdd(&deg[ei[NE + e]], 1);
}

__global__ __launch_bounds__(256) void scanA_kernel(
    const int* __restrict__ deg, int* __restrict__ cursor, int* __restrict__ partials)
{
    __shared__ int sh[256];
    int i = blockIdx.x * 256 + threadIdx.x;
    int v = (i < NN) ? deg[i] : 0;
    sh[threadIdx.x] = v;
    __syncthreads();
    for (int off = 1; off < 256; off <<= 1) {
        int t2 = (threadIdx.x >= off) ? sh[threadIdx.x - off] : 0;
        __syncthreads();
        sh[threadIdx.x] += t2;
        __syncthreads();
    }
    int incl = sh[threadIdx.x];
    if (i < NN) cursor[i] = incl - v;
    if (threadIdx.x == 255) partials[blockIdx.x] = incl;
}

__global__ __launch_bounds__(1024) void scanB_kernel(int* __restrict__ partials, int nb)
{
    __shared__ int sh[1024];
    int i = threadIdx.x;
    int v = (i < nb) ? partials[i] : 0;
    sh[i] = v;
    __syncthreads();
    for (int off = 1; off < 1024; off <<= 1) {
        int t2 = (i >= off) ? sh[i - off] : 0;
        __syncthreads();
        sh[i] += t2;
        __syncthreads();
    }
    if (i < nb) partials[i] = sh[i] - v;
}

__global__ __launch_bounds__(256) void scanC_kernel(
    int* __restrict__ cursor, const int* __restrict__ partials)
{
    int i = blockIdx.x * 256 + threadIdx.x;
    if (i < NN) cursor[i] += partials[blockIdx.x];
}

__global__ __launch_bounds__(256) void fill_kernel(
    const int* __restrict__ ei, int* __restrict__ cursor, int* __restrict__ csr_src)
{
    int e = blockIdx.x * 256 + threadIdx.x;
    if (e >= NE) return;
    int slot = atomicAdd(&cursor[ei[NE + e]], 1);
    csr_src[slot] = ei[e];
}

// graph_ptr[g] = first node index with batch >= g (batch sorted); gptr[NGRAPHS] = NN
__global__ __launch_bounds__(256) void gptr_kernel(
    const int* __restrict__ batch, int* __restrict__ gptr)
{
    int n = blockIdx.x * 256 + threadIdx.x;
    if (n > NN) return;
    int b1 = (n < NN) ? batch[n] : NGRAPHS;
    int b0 = (n == 0) ? -1 : batch[n - 1];
    for (int g = b0 + 1; g <= b1; ++g) gptr[g] = n;
}

__global__ void ident_kernel(float* __restrict__ aff)
{
    int d = threadIdx.x;
    aff[d] = 1.f;
    aff[DIM + d] = 0.f;
}

// ---------------- affine-fused gather ----------------
// agg[n] = a ⊙ (z[n] + sum_nbr z) + (deg+1)·c   (h never materialized)
__global__ __launch_bounds__(256) void gather_kernel(
    const unsigned short* __restrict__ z, const int* __restrict__ cursor,
    const int* __restrict__ csr_src, const float* __restrict__ aff,
    unsigned short* __restrict__ agg)
{
    int t = blockIdx.x * 256 + threadIdx.x;      // NN*16 exactly
    int n = t >> 4, j = t & 15;
    int end = cursor[n];
    int beg = (n == 0) ? 0 : cursor[n - 1];
    ushort8 sv = *(const ushort8*)(z + (size_t)n * DIM + j * 8);
    float a[8];
#pragma unroll
    for (int i = 0; i < 8; ++i) a[i] = bf2f(sv[i]);
    for (int e = beg; e < end; ++e) {
        int s = csr_src[e];
        ushort8 v = *(const ushort8*)(z + (size_t)s * DIM + j * 8);
#pragma unroll
        for (int i = 0; i < 8; ++i) a[i] += bf2f(v[i]);
    }
    float cnt = (float)(end - beg + 1);
    ushort8 o;
#pragma unroll
    for (int i = 0; i < 8; ++i) {
        float av = aff[j * 8 + i];
        float cv = aff[DIM + j * 8 + i];
        o[i] = f2bf(fmaf(av, a[i], cnt * cv));
    }
    *(ushort8*)(agg + (size_t)n * DIM + j * 8) = o;
}

// ---------------- per-graph pool: out[g] += lcw*(a⊙segsum(z) + cnt*c) (+ cnt*lcb) ----------------
__global__ __launch_bounds__(128) void pool_kernel(
    const unsigned short* __restrict__ z, const int* __restrict__ gptr,
    const float* __restrict__ aff, const float* __restrict__ lcw, int l,
    const float* __restrict__ lcb_p, int add_lcb, float* __restrict__ out)
{
    int g = blockIdx.x;
    int d = threadIdx.x;
    int p0 = gptr[g], p1 = gptr[g + 1];
    float S = 0.f;
    for (int n = p0; n < p1; ++n) S += bf2f(z[(size_t)n * DIM + d]);
    float w = lcw[l];
    float cnt = (float)(p1 - p0);
    float v = w * fmaf(aff[d], S, cnt * aff[DIM + d]);
    if (add_lcb) v = fmaf(cnt, *lcb_p, v);
    out[(size_t)g * DIM + d] += v;
}

// per-layer: affine[d] = gamma*rsqrt(var+eps); affine[128+d] = beta - mean*a
__global__ void finalize_kernel(
    const float* __restrict__ slots, const float* __restrict__ gamma,
    const float* __restrict__ beta, float* __restrict__ aff)
{
    int d = threadIdx.x;
    float s = 0.f, sq = 0.f;
    for (int i = 0; i < NSLOT; ++i) {
        s  += slots[i * 256 + d];
        sq += slots[i * 256 + 128 + d];
    }
    float mean = s * (1.0f / NN);
    float var = sq * (1.0f / NN) - mean * mean;
    float a = gamma[d] * rsqrtf(var + BN_EPS_C);
    aff[d] = a;
    aff[DIM + d] = beta[d] - mean * a;
}

extern "C" void kernel_launch(void* const* d_in, const int* in_sizes, int n_in,
                              void* d_out, int out_size, void* d_ws, size_t ws_size,
                              hipStream_t stream)
{
    const float* x      = (const float*)d_in[0];
    const int*   ei     = (const int*)d_in[1];
    const int*   batch  = (const int*)d_in[2];
    const float* ini_w1 = (const float*)d_in[4];
    const float* ini_b1 = (const float*)d_in[5];
    const float* ini_w2 = (const float*)d_in[6];
    const float* ini_b2 = (const float*)d_in[7];
    const float* gw1    = (const float*)d_in[8];
    const float* gb1    = (const float*)d_in[9];
    const float* gw2    = (const float*)d_in[10];
    const float* gb2    = (const float*)d_in[11];
    const float* gamma  = (const float*)d_in[12];
    const float* beta   = (const float*)d_in[13];
    const float* lcw    = (const float*)d_in[14];
    const float* lcb    = (const float*)d_in[15];
    float* out = (float*)d_out;

    size_t NHs = (size_t)NN * DIM;                       // ushort count per node buffer
    unsigned short* bufA = (unsigned short*)d_ws;
    unsigned short* bufB = bufA + NHs;                   // also holds padded x pre-ini
    unsigned short* Wd   = bufB + NHs;                   // 12 * 16384 ushorts
    float* stats  = (float*)(Wd + 12 * 16384);           // NLAYERS * NSLOT * 256
    float* affine = stats + (size_t)NLAYERS * NSLOT * 256; // (NLAYERS+1) * 256
    int* deg      = (int*)(affine + (NLAYERS + 1) * 256);
    int* cursor   = deg + NN;
    int* csr_src  = cursor + NN;
    int* partials = csr_src + NE;
    int* gptr     = partials + 1024;
    size_t need = (size_t)((char*)(gptr + NGRAPHS + 1) - (char*)d_ws);

    hipMemsetAsync(out, 0, (size_t)NGRAPHS * DIM * sizeof(float), stream);
    if (ws_size < need) return;   // diagnostic: zero output signals ws shortfall

    hipMemsetAsync(stats, 0, (size_t)NLAYERS * NSLOT * 256 * sizeof(float), stream);
    hipMemsetAsync(deg, 0, NN * sizeof(int), stream);

    int nb = (NN + 255) / 256;     // 782
    int eb = (NE + 255) / 256;

    deg_kernel<<<eb, 256, 0, stream>>>(ei, deg);
    scanA_kernel<<<nb, 256, 0, stream>>>(deg, cursor, partials);
    scanB_kernel<<<1, 1024, 0, stream>>>(partials, nb);
    scanC_kernel<<<nb, 256, 0, stream>>>(cursor, partials);
    fill_kernel<<<eb, 256, 0, stream>>>(ei, cursor, csr_src);
    gptr_kernel<<<(NN + 256) / 256 + 1, 256, 0, stream>>>(batch, gptr);
    ident_kernel<<<1, 128, 0, stream>>>(affine);

    xpad_kernel<<<NN * 16 / 256, 256, 0, stream>>>(x, bufB);
    wconv_kernel<<<dim3(64, 12), 256, 0, stream>>>(ini_w1, ini_w2, gw1, gw2, Wd);

    int gin_blocks = (NN + 127) / 128;   // 1563

    // ini_embed: bufA = relu(xp@W1+b1)@W2+b2 (no relu, no stats)
    gin_mlp_kernel<0, 0><<<gin_blocks, 256, 0, stream>>>(
        bufB, Wd, Wd + 16384, ini_b1, ini_b2, bufA, nullptr);

    unsigned short* prev = bufA;
    for (int l = 0; l < NLAYERS; ++l) {
        unsigned short* nxt = (prev == bufA) ? bufB : bufA;
        // nxt = a_{l-1} ⊙ (z_prev + Σ z_prev[nbr]) + (deg+1)·c_{l-1}
        gather_kernel<<<NN * 16 / 256, 256, 0, stream>>>(
            prev, cursor, csr_src, affine + (size_t)l * 256, nxt);
        // nxt = relu(relu(nxt@W1+b1)@W2+b2), in-place; stats fused
        gin_mlp_kernel<1, 1><<<gin_blocks, 256, 0, stream>>>(
            nxt, Wd + (size_t)(2 + l) * 16384, Wd + (size_t)(7 + l) * 16384,
            gb1 + l * DIM, gb2 + l * DIM, nxt, stats + (size_t)l * NSLOT * 256);
        finalize_kernel<<<1, 128, 0, stream>>>(
            stats + (size_t)l * NSLOT * 256, gamma + l * DIM, beta + l * DIM,
            affine + (size_t)(l + 1) * 256);
        // out += lcw[l]*(a_l ⊙ segsum(z_l) + cnt*c_l) (+ cnt*lcb on l==0)
        pool_kernel<<<NGRAPHS, 128, 0, stream>>>(
            nxt, gptr, affine + (size_t)(l + 1) * 256, lcw, l, lcb,
            (l == 0) ? 1 : 0, out);
        prev = nxt;
    }
}